// Round 1
// baseline (504.913 us; speedup 1.0000x reference)
//
#include <hip/hip_runtime.h>
#include <hip/hip_bf16.h>

// MoE: B=2,S=2048 -> T=4096 tokens, H=1024, F=2048, E=8, TOPK=2
#define TT 4096
#define HH 1024
#define FF 2048
#define EE 8

typedef short short8_t __attribute__((ext_vector_type(8)));
typedef float f32x4 __attribute__((ext_vector_type(4)));

__device__ __forceinline__ unsigned short f2b(float f) {
  union { float f; unsigned u; } v; v.f = f;
  return (unsigned short)((v.u + 0x7fffu + ((v.u >> 16) & 1u)) >> 16);  // RNE
}

__device__ __forceinline__ short8_t pack8(float4 a, float4 b) {
  short8_t r;
  r[0] = (short)f2b(a.x); r[1] = (short)f2b(a.y);
  r[2] = (short)f2b(a.z); r[3] = (short)f2b(a.w);
  r[4] = (short)f2b(b.x); r[5] = (short)f2b(b.y);
  r[6] = (short)f2b(b.z); r[7] = (short)f2b(b.w);
  return r;
}

// ---------------- Router: logits (f32, to d_out), top-2, token lists, x->bf16 ----
__global__ __launch_bounds__(256) void router_kernel(
    const float* __restrict__ x, const float* __restrict__ gw,
    float* __restrict__ out_logits, unsigned short* __restrict__ xbf,
    int* __restrict__ counts, int* __restrict__ tokidx, float* __restrict__ rww)
{
  int t = blockIdx.x;
  int tid = threadIdx.x;
  __shared__ float xs[HH];
  __shared__ float lg[EE];

  float4 v = reinterpret_cast<const float4*>(x + (size_t)t * HH)[tid];
  xs[tid * 4 + 0] = v.x; xs[tid * 4 + 1] = v.y;
  xs[tid * 4 + 2] = v.z; xs[tid * 4 + 3] = v.w;
  ushort4 b4;
  b4.x = f2b(v.x); b4.y = f2b(v.y); b4.z = f2b(v.z); b4.w = f2b(v.w);
  reinterpret_cast<ushort4*>(xbf + (size_t)t * HH)[tid] = b4;
  __syncthreads();

  int lane = tid & 63, wv = tid >> 6;
  for (int e = wv; e < EE; e += 4) {
    float s = 0.f;
    const float* g = gw + (size_t)e * HH;
#pragma unroll
    for (int j = 0; j < HH / 64; ++j) s += xs[lane + j * 64] * g[lane + j * 64];
#pragma unroll
    for (int off = 32; off > 0; off >>= 1) s += __shfl_down(s, off);
    if (lane == 0) lg[e] = s;
  }
  __syncthreads();

  if (tid == 0) {
    float l[EE];
#pragma unroll
    for (int e = 0; e < EE; ++e) {
      l[e] = lg[e];
      out_logits[(size_t)t * EE + e] = l[e];
    }
    int e0 = 0;
#pragma unroll
    for (int e = 1; e < EE; ++e) if (l[e] > l[e0]) e0 = e;
    int e1 = -1;
#pragma unroll
    for (int e = 0; e < EE; ++e) if (e != e0 && (e1 < 0 || l[e] > l[e1])) e1 = e;
    // softmax denominator cancels in rw normalization
    float p1 = expf(l[e1] - l[e0]);
    float w0 = 1.f / (1.f + p1);
    float w1v = p1 * w0;
    int pos0 = atomicAdd(&counts[e0], 1);
    tokidx[e0 * TT + pos0] = t; rww[e0 * TT + pos0] = w0;
    int pos1 = atomicAdd(&counts[e1], 1);
    tokidx[e1 * TT + pos1] = t; rww[e1 * TT + pos1] = w1v;
  }
}

// ---------------- Scan: 128-padded per-expert row offsets ----------------------
__global__ void scan_kernel(const int* __restrict__ counts, int* __restrict__ po) {
  if (threadIdx.x == 0 && blockIdx.x == 0) {
    int acc = 0;
    for (int e = 0; e < EE; ++e) {
      po[e] = acc;
      acc += (counts[e] + 127) & ~127;
    }
    po[EE] = acc;
  }
}

// ---------------- Up-proj + gate: gated = silu(x@w1^T) * (x@w3^T), bf16 out ----
__global__ __launch_bounds__(256) void up_gate_kernel(
    const unsigned short* __restrict__ xbf,
    const float* __restrict__ w1, const float* __restrict__ w3,
    const int* __restrict__ counts, const int* __restrict__ po,
    const int* __restrict__ tokidx,
    unsigned short* __restrict__ gated)
{
  int e = blockIdx.z;
  int n = counts[e];
  int row0 = blockIdx.y * 128;
  if (row0 >= n) return;
  int fbase = blockIdx.x * 128;
  int valid = min(128, n - row0);

  __shared__ unsigned short As[128][32];
  __shared__ unsigned short Bs1[128][32];
  __shared__ unsigned short Bs3[128][32];

  int tid = threadIdx.x;
  int sr = tid >> 1;          // staging row 0..127
  int so = (tid & 1) * 16;    // staging k-offset (elements)

  int tok = -1;
  if (sr < valid) tok = tokidx[e * TT + row0 + sr];
  const unsigned short* xrow = (tok >= 0) ? (xbf + (size_t)tok * HH) : nullptr;
  const float* w1e = w1 + (size_t)e * FF * HH + (size_t)(fbase + sr) * HH;
  const float* w3e = w3 + (size_t)e * FF * HH + (size_t)(fbase + sr) * HH;

  int lane = tid & 63, wv = tid >> 6;
  int wr = (wv >> 1) * 64, wc = (wv & 1) * 64;
  int fr = lane & 15, fk = (lane >> 4) * 8;

  f32x4 acc1[4][4], acc3[4][4];
#pragma unroll
  for (int m = 0; m < 4; ++m)
#pragma unroll
    for (int nn = 0; nn < 4; ++nn) { acc1[m][nn] = (f32x4)0.f; acc3[m][nn] = (f32x4)0.f; }

  for (int k0 = 0; k0 < HH; k0 += 32) {
    short8_t av0 = (short8_t)(short)0, av1 = (short8_t)(short)0;
    if (xrow) {
      av0 = *reinterpret_cast<const short8_t*>(xrow + k0 + so);
      av1 = *reinterpret_cast<const short8_t*>(xrow + k0 + so + 8);
    }
    const float* b1p = w1e + k0 + so;
    const float* b3p = w3e + k0 + so;
    short8_t b1v0 = pack8(*(const float4*)(b1p + 0), *(const float4*)(b1p + 4));
    short8_t b1v1 = pack8(*(const float4*)(b1p + 8), *(const float4*)(b1p + 12));
    short8_t b3v0 = pack8(*(const float4*)(b3p + 0), *(const float4*)(b3p + 4));
    short8_t b3v1 = pack8(*(const float4*)(b3p + 8), *(const float4*)(b3p + 12));

    __syncthreads();  // previous iter's fragment reads done
    *reinterpret_cast<short8_t*>(&As[sr][so])      = av0;
    *reinterpret_cast<short8_t*>(&As[sr][so + 8])  = av1;
    *reinterpret_cast<short8_t*>(&Bs1[sr][so])     = b1v0;
    *reinterpret_cast<short8_t*>(&Bs1[sr][so + 8]) = b1v1;
    *reinterpret_cast<short8_t*>(&Bs3[sr][so])     = b3v0;
    *reinterpret_cast<short8_t*>(&Bs3[sr][so + 8]) = b3v1;
    __syncthreads();

    short8_t a[4], b1f[4], b3f[4];
#pragma unroll
    for (int m = 0; m < 4; ++m)
      a[m] = *reinterpret_cast<const short8_t*>(&As[wr + m * 16 + fr][fk]);
#pragma unroll
    for (int nn = 0; nn < 4; ++nn) {
      b1f[nn] = *reinterpret_cast<const short8_t*>(&Bs1[wc + nn * 16 + fr][fk]);
      b3f[nn] = *reinterpret_cast<const short8_t*>(&Bs3[wc + nn * 16 + fr][fk]);
    }
#pragma unroll
    for (int m = 0; m < 4; ++m)
#pragma unroll
      for (int nn = 0; nn < 4; ++nn) {
        acc1[m][nn] = __builtin_amdgcn_mfma_f32_16x16x32_bf16(a[m], b1f[nn], acc1[m][nn], 0, 0, 0);
        acc3[m][nn] = __builtin_amdgcn_mfma_f32_16x16x32_bf16(a[m], b3f[nn], acc3[m][nn], 0, 0, 0);
      }
  }

  // epilogue: gated = silu(h1)*h3 -> bf16 (pad rows are exact zeros)
  size_t gbase = ((size_t)po[e] + row0) * FF + fbase;
#pragma unroll
  for (int m = 0; m < 4; ++m) {
#pragma unroll
    for (int nn = 0; nn < 4; ++nn) {
      f32x4 h1v = acc1[m][nn], h3v = acc3[m][nn];
#pragma unroll
      for (int j = 0; j < 4; ++j) {
        float z = h1v[j];
        float sg = z / (1.f + expf(-z));
        float val = sg * h3v[j];
        int r = wr + m * 16 + (lane >> 4) * 4 + j;
        int c = wc + nn * 16 + fr;
        gated[gbase + (size_t)r * FF + c] = f2b(val);
      }
    }
  }
}

// ---------------- Down-proj + weighted scatter into final ----------------------
__global__ __launch_bounds__(256) void down_kernel(
    const unsigned short* __restrict__ gated,
    const float* __restrict__ w2,
    const int* __restrict__ counts, const int* __restrict__ po,
    const int* __restrict__ tokidx, const float* __restrict__ rww,
    float* __restrict__ final_out)
{
  int e = blockIdx.z;
  int n = counts[e];
  int row0 = blockIdx.y * 128;
  if (row0 >= n) return;
  int hbase = blockIdx.x * 128;
  int valid = min(128, n - row0);

  __shared__ unsigned short As[128][32];
  __shared__ unsigned short Bs[128][32];

  int tid = threadIdx.x;
  int sr = tid >> 1;
  int so = (tid & 1) * 16;

  const unsigned short* arow = gated + ((size_t)po[e] + row0 + sr) * FF;
  const float* w2e = w2 + (size_t)e * HH * FF + (size_t)(hbase + sr) * FF;

  int lane = tid & 63, wv = tid >> 6;
  int wr = (wv >> 1) * 64, wc = (wv & 1) * 64;
  int fr = lane & 15, fk = (lane >> 4) * 8;

  f32x4 acc[4][4];
#pragma unroll
  for (int m = 0; m < 4; ++m)
#pragma unroll
    for (int nn = 0; nn < 4; ++nn) acc[m][nn] = (f32x4)0.f;

  for (int k0 = 0; k0 < FF; k0 += 32) {
    short8_t av0 = *reinterpret_cast<const short8_t*>(arow + k0 + so);
    short8_t av1 = *reinterpret_cast<const short8_t*>(arow + k0 + so + 8);
    const float* bp = w2e + k0 + so;
    short8_t bv0 = pack8(*(const float4*)(bp + 0), *(const float4*)(bp + 4));
    short8_t bv1 = pack8(*(const float4*)(bp + 8), *(const float4*)(bp + 12));

    __syncthreads();
    *reinterpret_cast<short8_t*>(&As[sr][so])     = av0;
    *reinterpret_cast<short8_t*>(&As[sr][so + 8]) = av1;
    *reinterpret_cast<short8_t*>(&Bs[sr][so])     = bv0;
    *reinterpret_cast<short8_t*>(&Bs[sr][so + 8]) = bv1;
    __syncthreads();

    short8_t a[4], bf[4];
#pragma unroll
    for (int m = 0; m < 4; ++m)
      a[m] = *reinterpret_cast<const short8_t*>(&As[wr + m * 16 + fr][fk]);
#pragma unroll
    for (int nn = 0; nn < 4; ++nn)
      bf[nn] = *reinterpret_cast<const short8_t*>(&Bs[wc + nn * 16 + fr][fk]);
#pragma unroll
    for (int m = 0; m < 4; ++m)
#pragma unroll
      for (int nn = 0; nn < 4; ++nn)
        acc[m][nn] = __builtin_amdgcn_mfma_f32_16x16x32_bf16(a[m], bf[nn], acc[m][nn], 0, 0, 0);
  }

  // epilogue: final[t, h] += rw * out  (each token gets exactly 2 expert adds)
#pragma unroll
  for (int m = 0; m < 4; ++m) {
    int rbase = wr + m * 16 + (lane >> 4) * 4;
#pragma unroll
    for (int j = 0; j < 4; ++j) {
      int r = rbase + j;
      if (r < valid) {
        int t = tokidx[e * TT + row0 + r];
        float w = rww[e * TT + row0 + r];
#pragma unroll
        for (int nn = 0; nn < 4; ++nn) {
          int c = hbase + wc + nn * 16 + fr;
          atomicAdd(&final_out[(size_t)t * HH + c], w * acc[m][nn][j]);
        }
      }
    }
  }
}

extern "C" void kernel_launch(void* const* d_in, const int* in_sizes, int n_in,
                              void* d_out, int out_size, void* d_ws, size_t ws_size,
                              hipStream_t stream) {
  const float* x  = (const float*)d_in[0];   // [T, H]
  const float* gw = (const float*)d_in[1];   // [E, H]
  const float* w1 = (const float*)d_in[2];   // [E, F, H]
  const float* w2 = (const float*)d_in[3];   // [E, H, F]
  const float* w3 = (const float*)d_in[4];   // [E, F, H]

  float* final_out  = (float*)d_out;                       // [T, H]
  float* out_logits = final_out + (size_t)TT * HH;         // [T, E]

  char* ws = (char*)d_ws;
  int*   counts = (int*)(ws + 0);                           // 32 B
  int*   po     = (int*)(ws + 64);                          // 36 B
  int*   tokidx = (int*)(ws + 128);                         // E*T*4 = 131072
  float* rww    = (float*)(ws + 128 + 131072);              // 131072
  unsigned short* xbf   = (unsigned short*)(ws + 262272);   // T*H*2 = 8388608
  unsigned short* gated = (unsigned short*)(ws + 8650880);  // 9216*F*2 = 37748736

  hipMemsetAsync(counts, 0, 64, stream);
  hipMemsetAsync(final_out, 0, (size_t)TT * HH * sizeof(float), stream);

  router_kernel<<<TT, 256, 0, stream>>>(x, gw, out_logits, xbf, counts, tokidx, rww);
  scan_kernel<<<1, 64, 0, stream>>>(counts, po);
  up_gate_kernel<<<dim3(FF / 128, TT / 128, EE), 256, 0, stream>>>(
      xbf, w1, w3, counts, po, tokidx, gated);
  down_kernel<<<dim3(HH / 128, TT / 128, EE), 256, 0, stream>>>(
      gated, w2, counts, po, tokidx, rww, final_out);
}

// Round 2
// 374.384 us; speedup vs baseline: 1.3486x; 1.3486x over previous
//
#include <hip/hip_runtime.h>
#include <hip/hip_bf16.h>

// MoE: B=2,S=2048 -> T=4096 tokens, H=1024, F=2048, E=8, TOPK=2
#define TT 4096
#define HH 1024
#define FF 2048
#define EE 8

typedef short short8_t __attribute__((ext_vector_type(8)));
typedef float f32x4 __attribute__((ext_vector_type(4)));

__device__ __forceinline__ unsigned short f2b(float f) {
  union { float f; unsigned u; } v; v.f = f;
  return (unsigned short)((v.u + 0x7fffu + ((v.u >> 16) & 1u)) >> 16);  // RNE
}

__device__ __forceinline__ short8_t pack8(float4 a, float4 b) {
  short8_t r;
  r[0] = (short)f2b(a.x); r[1] = (short)f2b(a.y);
  r[2] = (short)f2b(a.z); r[3] = (short)f2b(a.w);
  r[4] = (short)f2b(b.x); r[5] = (short)f2b(b.y);
  r[6] = (short)f2b(b.z); r[7] = (short)f2b(b.w);
  return r;
}

__device__ __forceinline__ void gload16(const unsigned short* g, unsigned short* l) {
  __builtin_amdgcn_global_load_lds(
      (const __attribute__((address_space(1))) void*)g,
      (__attribute__((address_space(3))) void*)l, 16, 0, 0);
}

// ---------------- Weight conversion: f32 -> bf16, 8 elems/thread ---------------
__global__ __launch_bounds__(256) void conv_kernel(
    const float* __restrict__ src, unsigned short* __restrict__ dst)
{
  size_t i = ((size_t)blockIdx.x * 256 + threadIdx.x) * 8;
  float4 a = *reinterpret_cast<const float4*>(src + i);
  float4 b = *reinterpret_cast<const float4*>(src + i + 4);
  *reinterpret_cast<short8_t*>(dst + i) = pack8(a, b);
}

// ---------------- Router: logits (f32, to d_out), top-2, token lists, x->bf16 ----
__global__ __launch_bounds__(256) void router_kernel(
    const float* __restrict__ x, const float* __restrict__ gw,
    float* __restrict__ out_logits, unsigned short* __restrict__ xbf,
    int* __restrict__ counts, int* __restrict__ tokidx, float* __restrict__ rww)
{
  int t = blockIdx.x;
  int tid = threadIdx.x;
  __shared__ float xs[HH];
  __shared__ float lg[EE];

  float4 v = reinterpret_cast<const float4*>(x + (size_t)t * HH)[tid];
  xs[tid * 4 + 0] = v.x; xs[tid * 4 + 1] = v.y;
  xs[tid * 4 + 2] = v.z; xs[tid * 4 + 3] = v.w;
  ushort4 b4;
  b4.x = f2b(v.x); b4.y = f2b(v.y); b4.z = f2b(v.z); b4.w = f2b(v.w);
  reinterpret_cast<ushort4*>(xbf + (size_t)t * HH)[tid] = b4;
  __syncthreads();

  int lane = tid & 63, wv = tid >> 6;
  for (int e = wv; e < EE; e += 4) {
    float s = 0.f;
    const float* g = gw + (size_t)e * HH;
#pragma unroll
    for (int j = 0; j < HH / 64; ++j) s += xs[lane + j * 64] * g[lane + j * 64];
#pragma unroll
    for (int off = 32; off > 0; off >>= 1) s += __shfl_down(s, off);
    if (lane == 0) lg[e] = s;
  }
  __syncthreads();

  if (tid == 0) {
    float l[EE];
#pragma unroll
    for (int e = 0; e < EE; ++e) {
      l[e] = lg[e];
      out_logits[(size_t)t * EE + e] = l[e];
    }
    int e0 = 0;
#pragma unroll
    for (int e = 1; e < EE; ++e) if (l[e] > l[e0]) e0 = e;
    int e1 = -1;
#pragma unroll
    for (int e = 0; e < EE; ++e) if (e != e0 && (e1 < 0 || l[e] > l[e1])) e1 = e;
    float p1 = expf(l[e1] - l[e0]);
    float w0 = 1.f / (1.f + p1);
    float w1v = p1 * w0;
    int pos0 = atomicAdd(&counts[e0], 1);
    tokidx[e0 * TT + pos0] = t; rww[e0 * TT + pos0] = w0;
    int pos1 = atomicAdd(&counts[e1], 1);
    tokidx[e1 * TT + pos1] = t; rww[e1 * TT + pos1] = w1v;
  }
}

// ---------------- Scan: 128-padded per-expert row offsets ----------------------
__global__ void scan_kernel(const int* __restrict__ counts, int* __restrict__ po) {
  if (threadIdx.x == 0 && blockIdx.x == 0) {
    int acc = 0;
    for (int e = 0; e < EE; ++e) {
      po[e] = acc;
      acc += (counts[e] + 127) & ~127;
    }
    po[EE] = acc;
  }
}

// ---------------- Up-proj + gate: tile 128 tokens x 64 F, both w1 & w3 ---------
// m97-style: global_load_lds(16B) staging, 2 barriers/K-step, BK=32.
__global__ __launch_bounds__(256) void up_gate_kernel(
    const unsigned short* __restrict__ xbf,
    const unsigned short* __restrict__ w1bf, const unsigned short* __restrict__ w3bf,
    const int* __restrict__ counts, const int* __restrict__ po,
    const int* __restrict__ tokidx,
    unsigned short* __restrict__ gated)
{
  int e = blockIdx.z;
  int n = counts[e];
  int row0 = blockIdx.y * 128;
  if (row0 >= n) return;
  int fbase = blockIdx.x * 64;

  __shared__ unsigned short As[128 * 32];   // 8 KB
  __shared__ unsigned short B1s[64 * 32];   // 4 KB
  __shared__ unsigned short B3s[64 * 32];   // 4 KB

  int tid = threadIdx.x;
  int lane = tid & 63, wv = tid >> 6;

  // staging geometry: 64 lanes x 16B = 1KB = 16 rows of [32] bf16
  int srow = wv * 16 + (lane >> 2);      // 0..63
  int skoff = (lane & 3) * 8;            // k-offset (elements)

  // gathered token rows (clamp pads to a valid token; pad outputs are discarded)
  int r0 = min(row0 + srow, n - 1);
  int r1 = min(row0 + 64 + srow, n - 1);
  int t0 = tokidx[e * TT + r0];
  int t1 = tokidx[e * TT + r1];
  const unsigned short* ga0 = xbf + (size_t)t0 * HH + skoff;
  const unsigned short* ga1 = xbf + (size_t)t1 * HH + skoff;
  const unsigned short* gb1 = w1bf + ((size_t)e * FF + fbase + srow) * HH + skoff;
  const unsigned short* gb3 = w3bf + ((size_t)e * FF + fbase + srow) * HH + skoff;

  int wr = (wv >> 1) * 64, wc = (wv & 1) * 32;
  int fr = lane & 15, fk = (lane >> 4) * 8;

  f32x4 acc1[4][2], acc3[4][2];
#pragma unroll
  for (int m = 0; m < 4; ++m)
#pragma unroll
    for (int nn = 0; nn < 2; ++nn) { acc1[m][nn] = (f32x4)0.f; acc3[m][nn] = (f32x4)0.f; }

  for (int k0 = 0; k0 < HH; k0 += 32) {
    __syncthreads();  // prior tile's ds_reads done before overwrite
    gload16(ga0 + k0, &As[wv * 512]);
    gload16(ga1 + k0, &As[2048 + wv * 512]);
    gload16(gb1 + k0, &B1s[wv * 512]);
    gload16(gb3 + k0, &B3s[wv * 512]);
    asm volatile("s_waitcnt vmcnt(0)" ::: "memory");
    __syncthreads();  // tile visible

    short8_t a[4], b1f[2], b3f[2];
#pragma unroll
    for (int m = 0; m < 4; ++m)
      a[m] = *reinterpret_cast<const short8_t*>(&As[(wr + m * 16 + fr) * 32 + fk]);
#pragma unroll
    for (int nn = 0; nn < 2; ++nn) {
      b1f[nn] = *reinterpret_cast<const short8_t*>(&B1s[(wc + nn * 16 + fr) * 32 + fk]);
      b3f[nn] = *reinterpret_cast<const short8_t*>(&B3s[(wc + nn * 16 + fr) * 32 + fk]);
    }
#pragma unroll
    for (int m = 0; m < 4; ++m)
#pragma unroll
      for (int nn = 0; nn < 2; ++nn) {
        acc1[m][nn] = __builtin_amdgcn_mfma_f32_16x16x32_bf16(a[m], b1f[nn], acc1[m][nn], 0, 0, 0);
        acc3[m][nn] = __builtin_amdgcn_mfma_f32_16x16x32_bf16(a[m], b3f[nn], acc3[m][nn], 0, 0, 0);
      }
  }

  // epilogue: gated = silu(h1)*h3 -> bf16
  size_t gbase = ((size_t)po[e] + row0) * FF + fbase;
#pragma unroll
  for (int m = 0; m < 4; ++m) {
#pragma unroll
    for (int nn = 0; nn < 2; ++nn) {
      f32x4 h1v = acc1[m][nn], h3v = acc3[m][nn];
#pragma unroll
      for (int j = 0; j < 4; ++j) {
        float z = h1v[j];
        float val = (z / (1.f + expf(-z))) * h3v[j];
        int r = wr + m * 16 + (lane >> 4) * 4 + j;
        int c = wc + nn * 16 + fr;
        gated[gbase + (size_t)r * FF + c] = f2b(val);
      }
    }
  }
}

// ---------------- Down-proj + weighted scatter: tile 128 x 128, K=F ------------
__global__ __launch_bounds__(256) void down_kernel(
    const unsigned short* __restrict__ gated,
    const unsigned short* __restrict__ w2bf,
    const int* __restrict__ counts, const int* __restrict__ po,
    const int* __restrict__ tokidx, const float* __restrict__ rww,
    float* __restrict__ final_out)
{
  int e = blockIdx.z;
  int n = counts[e];
  int row0 = blockIdx.y * 128;
  if (row0 >= n) return;
  int hbase = blockIdx.x * 128;
  int valid = min(128, n - row0);

  __shared__ unsigned short As[128 * 32];   // 8 KB
  __shared__ unsigned short Bs[128 * 32];   // 8 KB

  int tid = threadIdx.x;
  int lane = tid & 63, wv = tid >> 6;
  int srow = wv * 16 + (lane >> 2);
  int skoff = (lane & 3) * 8;

  const unsigned short* ga0 = gated + ((size_t)po[e] + row0 + srow) * FF + skoff;
  const unsigned short* ga1 = ga0 + (size_t)64 * FF;
  const unsigned short* gb0 = w2bf + ((size_t)e * HH + hbase + srow) * FF + skoff;
  const unsigned short* gb1 = gb0 + (size_t)64 * FF;

  int wr = (wv >> 1) * 64, wc = (wv & 1) * 64;
  int fr = lane & 15, fk = (lane >> 4) * 8;

  f32x4 acc[4][4];
#pragma unroll
  for (int m = 0; m < 4; ++m)
#pragma unroll
    for (int nn = 0; nn < 4; ++nn) acc[m][nn] = (f32x4)0.f;

  for (int k0 = 0; k0 < FF; k0 += 32) {
    __syncthreads();
    gload16(ga0 + k0, &As[wv * 512]);
    gload16(ga1 + k0, &As[2048 + wv * 512]);
    gload16(gb0 + k0, &Bs[wv * 512]);
    gload16(gb1 + k0, &Bs[2048 + wv * 512]);
    asm volatile("s_waitcnt vmcnt(0)" ::: "memory");
    __syncthreads();

    short8_t a[4], bf[4];
#pragma unroll
    for (int m = 0; m < 4; ++m)
      a[m] = *reinterpret_cast<const short8_t*>(&As[(wr + m * 16 + fr) * 32 + fk]);
#pragma unroll
    for (int nn = 0; nn < 4; ++nn)
      bf[nn] = *reinterpret_cast<const short8_t*>(&Bs[(wc + nn * 16 + fr) * 32 + fk]);
#pragma unroll
    for (int m = 0; m < 4; ++m)
#pragma unroll
      for (int nn = 0; nn < 4; ++nn)
        acc[m][nn] = __builtin_amdgcn_mfma_f32_16x16x32_bf16(a[m], bf[nn], acc[m][nn], 0, 0, 0);
  }

  // epilogue: final[t, h] += rw * out  (2 commutative f32 adds per element)
#pragma unroll
  for (int m = 0; m < 4; ++m) {
    int rbase = wr + m * 16 + (lane >> 4) * 4;
#pragma unroll
    for (int j = 0; j < 4; ++j) {
      int r = rbase + j;
      if (r < valid) {
        int t = tokidx[e * TT + row0 + r];
        float w = rww[e * TT + row0 + r];
#pragma unroll
        for (int nn = 0; nn < 4; ++nn) {
          int c = hbase + wc + nn * 16 + fr;
          atomicAdd(&final_out[(size_t)t * HH + c], w * acc[m][nn][j]);
        }
      }
    }
  }
}

extern "C" void kernel_launch(void* const* d_in, const int* in_sizes, int n_in,
                              void* d_out, int out_size, void* d_ws, size_t ws_size,
                              hipStream_t stream) {
  const float* x  = (const float*)d_in[0];   // [T, H]
  const float* gw = (const float*)d_in[1];   // [E, H]
  const float* w1 = (const float*)d_in[2];   // [E, F, H]
  const float* w2 = (const float*)d_in[3];   // [E, H, F]
  const float* w3 = (const float*)d_in[4];   // [E, F, H]

  float* final_out  = (float*)d_out;                       // [T, H]
  float* out_logits = final_out + (size_t)TT * HH;         // [T, E]

  char* ws = (char*)d_ws;
  int*   counts = (int*)(ws + 0);                             // 32 B
  int*   po     = (int*)(ws + 64);                            // 36 B
  int*   tokidx = (int*)(ws + 128);                           // 131072 B
  float* rww    = (float*)(ws + 128 + 131072);                // 131072 B
  unsigned short* xbf   = (unsigned short*)(ws + 262272);     // T*H*2   = 8388608
  unsigned short* wAbf  = (unsigned short*)(ws + 8650880);    // 33554432 (w1; later w2)
  unsigned short* w3bf  = (unsigned short*)(ws + 42205312);   // 33554432
  unsigned short* gated = (unsigned short*)(ws + 75759744);   // 9216*F*2 = 37748736
  // total ws use: 113,508,480 bytes

  hipMemsetAsync(counts, 0, 64, stream);
  hipMemsetAsync(final_out, 0, (size_t)TT * HH * sizeof(float), stream);

  const int nconv = (EE * FF * HH) / (256 * 8);  // 8192 blocks, exact
  conv_kernel<<<nconv, 256, 0, stream>>>(w1, wAbf);
  conv_kernel<<<nconv, 256, 0, stream>>>(w3, w3bf);
  router_kernel<<<TT, 256, 0, stream>>>(x, gw, out_logits, xbf, counts, tokidx, rww);
  scan_kernel<<<1, 64, 0, stream>>>(counts, po);
  up_gate_kernel<<<dim3(FF / 64, TT / 128, EE), 256, 0, stream>>>(
      xbf, wAbf, w3bf, counts, po, tokidx, gated);
  conv_kernel<<<nconv, 256, 0, stream>>>(w2, wAbf);  // reuse w1's buffer for w2
  down_kernel<<<dim3(HH / 128, TT / 128, EE), 256, 0, stream>>>(
      gated, wAbf, counts, po, tokidx, rww, final_out);
}

// Round 3
// 355.074 us; speedup vs baseline: 1.4220x; 1.0544x over previous
//
#include <hip/hip_runtime.h>
#include <hip/hip_bf16.h>

// MoE: B=2,S=2048 -> T=4096 tokens, H=1024, F=2048, E=8, TOPK=2
#define TT 4096
#define HH 1024
#define FF 2048
#define EE 8

typedef short short8_t __attribute__((ext_vector_type(8)));
typedef float f32x4 __attribute__((ext_vector_type(4)));

__device__ __forceinline__ unsigned short f2b(float f) {
  union { float f; unsigned u; } v; v.f = f;
  return (unsigned short)((v.u + 0x7fffu + ((v.u >> 16) & 1u)) >> 16);  // RNE
}

__device__ __forceinline__ short8_t pack8(float4 a, float4 b) {
  short8_t r;
  r[0] = (short)f2b(a.x); r[1] = (short)f2b(a.y);
  r[2] = (short)f2b(a.z); r[3] = (short)f2b(a.w);
  r[4] = (short)f2b(b.x); r[5] = (short)f2b(b.y);
  r[6] = (short)f2b(b.z); r[7] = (short)f2b(b.w);
  return r;
}

__device__ __forceinline__ void gload16(const unsigned short* g, unsigned short* l) {
  __builtin_amdgcn_global_load_lds(
      (const __attribute__((address_space(1))) void*)g,
      (__attribute__((address_space(3))) void*)l, 16, 0, 0);
}

// ---------------- Weight conversion: f32 -> bf16, 8 elems/thread ---------------
__global__ __launch_bounds__(256) void conv_kernel(
    const float* __restrict__ src, unsigned short* __restrict__ dst)
{
  size_t i = ((size_t)blockIdx.x * 256 + threadIdx.x) * 8;
  float4 a = *reinterpret_cast<const float4*>(src + i);
  float4 b = *reinterpret_cast<const float4*>(src + i + 4);
  *reinterpret_cast<short8_t*>(dst + i) = pack8(a, b);
}

// ---------------- Router: logits (f32, to d_out), top-2, token lists, x->bf16 ----
__global__ __launch_bounds__(256) void router_kernel(
    const float* __restrict__ x, const float* __restrict__ gw,
    float* __restrict__ out_logits, unsigned short* __restrict__ xbf,
    int* __restrict__ counts, int* __restrict__ tokidx, float* __restrict__ rww)
{
  int t = blockIdx.x;
  int tid = threadIdx.x;
  __shared__ float xs[HH];
  __shared__ float lg[EE];

  float4 v = reinterpret_cast<const float4*>(x + (size_t)t * HH)[tid];
  xs[tid * 4 + 0] = v.x; xs[tid * 4 + 1] = v.y;
  xs[tid * 4 + 2] = v.z; xs[tid * 4 + 3] = v.w;
  ushort4 b4;
  b4.x = f2b(v.x); b4.y = f2b(v.y); b4.z = f2b(v.z); b4.w = f2b(v.w);
  reinterpret_cast<ushort4*>(xbf + (size_t)t * HH)[tid] = b4;
  __syncthreads();

  int lane = tid & 63, wv = tid >> 6;
  for (int e = wv; e < EE; e += 4) {
    float s = 0.f;
    const float* g = gw + (size_t)e * HH;
#pragma unroll
    for (int j = 0; j < HH / 64; ++j) s += xs[lane + j * 64] * g[lane + j * 64];
#pragma unroll
    for (int off = 32; off > 0; off >>= 1) s += __shfl_down(s, off);
    if (lane == 0) lg[e] = s;
  }
  __syncthreads();

  if (tid == 0) {
    float l[EE];
#pragma unroll
    for (int e = 0; e < EE; ++e) {
      l[e] = lg[e];
      out_logits[(size_t)t * EE + e] = l[e];
    }
    int e0 = 0;
#pragma unroll
    for (int e = 1; e < EE; ++e) if (l[e] > l[e0]) e0 = e;
    int e1 = -1;
#pragma unroll
    for (int e = 0; e < EE; ++e) if (e != e0 && (e1 < 0 || l[e] > l[e1])) e1 = e;
    float p1 = expf(l[e1] - l[e0]);
    float w0 = 1.f / (1.f + p1);
    float w1v = p1 * w0;
    int pos0 = atomicAdd(&counts[e0], 1);
    tokidx[e0 * TT + pos0] = t; rww[e0 * TT + pos0] = w0;
    int pos1 = atomicAdd(&counts[e1], 1);
    tokidx[e1 * TT + pos1] = t; rww[e1 * TT + pos1] = w1v;
  }
}

// ---------------- Scan: 128-padded per-expert row offsets ----------------------
__global__ void scan_kernel(const int* __restrict__ counts, int* __restrict__ po) {
  if (threadIdx.x == 0 && blockIdx.x == 0) {
    int acc = 0;
    for (int e = 0; e < EE; ++e) {
      po[e] = acc;
      acc += (counts[e] + 127) & ~127;
    }
    po[EE] = acc;
  }
}

// ---------------- Up-proj + gate: 2-phase double-buffered, tile 128 x (64F x 2) -
__global__ __launch_bounds__(256) void up_gate_kernel(
    const unsigned short* __restrict__ xbf,
    const unsigned short* __restrict__ w1bf, const unsigned short* __restrict__ w3bf,
    const int* __restrict__ counts, const int* __restrict__ po,
    const int* __restrict__ tokidx,
    unsigned short* __restrict__ gated)
{
  int e = blockIdx.z;
  int n = counts[e];
  int row0 = blockIdx.y * 128;
  if (row0 >= n) return;
  int fbase = blockIdx.x * 64;

  __shared__ unsigned short As[2][128 * 32];   // 2 x 8 KB
  __shared__ unsigned short B1s[2][64 * 32];   // 2 x 4 KB
  __shared__ unsigned short B3s[2][64 * 32];   // 2 x 4 KB

  int tid = threadIdx.x;
  int lane = tid & 63, wv = tid >> 6;

  // staging geometry: 64 lanes x 16B = 1KB = 16 rows of [32] bf16
  int srow = wv * 16 + (lane >> 2);      // 0..63
  int skoff = (lane & 3) * 8;            // k-offset (elements)

  int r0 = min(row0 + srow, n - 1);
  int r1 = min(row0 + 64 + srow, n - 1);
  int t0 = tokidx[e * TT + r0];
  int t1 = tokidx[e * TT + r1];
  const unsigned short* ga0 = xbf + (size_t)t0 * HH + skoff;
  const unsigned short* ga1 = xbf + (size_t)t1 * HH + skoff;
  const unsigned short* gb1 = w1bf + ((size_t)e * FF + fbase + srow) * HH + skoff;
  const unsigned short* gb3 = w3bf + ((size_t)e * FF + fbase + srow) * HH + skoff;

  int wr = (wv >> 1) * 64, wc = (wv & 1) * 32;
  int fr = lane & 15, fk = (lane >> 4) * 8;

  f32x4 acc1[4][2], acc3[4][2];
#pragma unroll
  for (int m = 0; m < 4; ++m)
#pragma unroll
    for (int nn = 0; nn < 2; ++nn) { acc1[m][nn] = (f32x4)0.f; acc3[m][nn] = (f32x4)0.f; }

  // prologue: stage tile 0 into buf 0
  gload16(ga0, &As[0][wv * 512]);
  gload16(ga1, &As[0][2048 + wv * 512]);
  gload16(gb1, &B1s[0][wv * 512]);
  gload16(gb3, &B3s[0][wv * 512]);

  int cur = 0;
  for (int k0 = 0; k0 < HH; k0 += 32) {
    __syncthreads();  // implicit vmcnt(0)+lgkmcnt(0): buf[cur] staged, prior reads drained
    if (k0 + 32 < HH) {
      int nxt = cur ^ 1, kn = k0 + 32;
      gload16(ga0 + kn, &As[nxt][wv * 512]);
      gload16(ga1 + kn, &As[nxt][2048 + wv * 512]);
      gload16(gb1 + kn, &B1s[nxt][wv * 512]);
      gload16(gb3 + kn, &B3s[nxt][wv * 512]);
    }

    short8_t a[4], b1f[2], b3f[2];
#pragma unroll
    for (int m = 0; m < 4; ++m)
      a[m] = *reinterpret_cast<const short8_t*>(&As[cur][(wr + m * 16 + fr) * 32 + fk]);
#pragma unroll
    for (int nn = 0; nn < 2; ++nn) {
      b1f[nn] = *reinterpret_cast<const short8_t*>(&B1s[cur][(wc + nn * 16 + fr) * 32 + fk]);
      b3f[nn] = *reinterpret_cast<const short8_t*>(&B3s[cur][(wc + nn * 16 + fr) * 32 + fk]);
    }
#pragma unroll
    for (int m = 0; m < 4; ++m)
#pragma unroll
      for (int nn = 0; nn < 2; ++nn) {
        acc1[m][nn] = __builtin_amdgcn_mfma_f32_16x16x32_bf16(a[m], b1f[nn], acc1[m][nn], 0, 0, 0);
        acc3[m][nn] = __builtin_amdgcn_mfma_f32_16x16x32_bf16(a[m], b3f[nn], acc3[m][nn], 0, 0, 0);
      }
    cur ^= 1;
  }

  // epilogue: gated = silu(h1)*h3 -> bf16
  size_t gbase = ((size_t)po[e] + row0) * FF + fbase;
#pragma unroll
  for (int m = 0; m < 4; ++m) {
#pragma unroll
    for (int nn = 0; nn < 2; ++nn) {
      f32x4 h1v = acc1[m][nn], h3v = acc3[m][nn];
#pragma unroll
      for (int j = 0; j < 4; ++j) {
        float z = h1v[j];
        float val = (z / (1.f + expf(-z))) * h3v[j];
        int r = wr + m * 16 + (lane >> 4) * 4 + j;
        int c = wc + nn * 16 + fr;
        gated[gbase + (size_t)r * FF + c] = f2b(val);
      }
    }
  }
}

// ---------------- Down-proj + weighted scatter: 2-phase dbuf, tile 128 x 128 ----
__global__ __launch_bounds__(256) void down_kernel(
    const unsigned short* __restrict__ gated,
    const unsigned short* __restrict__ w2bf,
    const int* __restrict__ counts, const int* __restrict__ po,
    const int* __restrict__ tokidx, const float* __restrict__ rww,
    float* __restrict__ final_out)
{
  int e = blockIdx.z;
  int n = counts[e];
  int row0 = blockIdx.y * 128;
  if (row0 >= n) return;
  int hbase = blockIdx.x * 128;
  int valid = min(128, n - row0);

  __shared__ unsigned short As[2][128 * 32];   // 2 x 8 KB
  __shared__ unsigned short Bs[2][128 * 32];   // 2 x 8 KB

  int tid = threadIdx.x;
  int lane = tid & 63, wv = tid >> 6;
  int srow = wv * 16 + (lane >> 2);
  int skoff = (lane & 3) * 8;

  const unsigned short* ga0 = gated + ((size_t)po[e] + row0 + srow) * FF + skoff;
  const unsigned short* ga1 = ga0 + (size_t)64 * FF;
  const unsigned short* gb0 = w2bf + ((size_t)e * HH + hbase + srow) * FF + skoff;
  const unsigned short* gb1 = gb0 + (size_t)64 * FF;

  int wr = (wv >> 1) * 64, wc = (wv & 1) * 64;
  int fr = lane & 15, fk = (lane >> 4) * 8;

  f32x4 acc[4][4];
#pragma unroll
  for (int m = 0; m < 4; ++m)
#pragma unroll
    for (int nn = 0; nn < 4; ++nn) acc[m][nn] = (f32x4)0.f;

  // prologue: stage tile 0 into buf 0
  gload16(ga0, &As[0][wv * 512]);
  gload16(ga1, &As[0][2048 + wv * 512]);
  gload16(gb0, &Bs[0][wv * 512]);
  gload16(gb1, &Bs[0][2048 + wv * 512]);

  int cur = 0;
  for (int k0 = 0; k0 < FF; k0 += 32) {
    __syncthreads();  // implicit vmcnt(0)+lgkmcnt(0)
    if (k0 + 32 < FF) {
      int nxt = cur ^ 1, kn = k0 + 32;
      gload16(ga0 + kn, &As[nxt][wv * 512]);
      gload16(ga1 + kn, &As[nxt][2048 + wv * 512]);
      gload16(gb0 + kn, &Bs[nxt][wv * 512]);
      gload16(gb1 + kn, &Bs[nxt][2048 + wv * 512]);
    }

    short8_t a[4], bf[4];
#pragma unroll
    for (int m = 0; m < 4; ++m)
      a[m] = *reinterpret_cast<const short8_t*>(&As[cur][(wr + m * 16 + fr) * 32 + fk]);
#pragma unroll
    for (int nn = 0; nn < 4; ++nn)
      bf[nn] = *reinterpret_cast<const short8_t*>(&Bs[cur][(wc + nn * 16 + fr) * 32 + fk]);
#pragma unroll
    for (int m = 0; m < 4; ++m)
#pragma unroll
      for (int nn = 0; nn < 4; ++nn)
        acc[m][nn] = __builtin_amdgcn_mfma_f32_16x16x32_bf16(a[m], bf[nn], acc[m][nn], 0, 0, 0);
    cur ^= 1;
  }

  // epilogue: final[t, h] += rw * out  (2 commutative f32 adds per element)
#pragma unroll
  for (int m = 0; m < 4; ++m) {
    int rbase = wr + m * 16 + (lane >> 4) * 4;
#pragma unroll
    for (int j = 0; j < 4; ++j) {
      int r = rbase + j;
      if (r < valid) {
        int t = tokidx[e * TT + row0 + r];
        float w = rww[e * TT + row0 + r];
#pragma unroll
        for (int nn = 0; nn < 4; ++nn) {
          int c = hbase + wc + nn * 16 + fr;
          atomicAdd(&final_out[(size_t)t * HH + c], w * acc[m][nn][j]);
        }
      }
    }
  }
}

extern "C" void kernel_launch(void* const* d_in, const int* in_sizes, int n_in,
                              void* d_out, int out_size, void* d_ws, size_t ws_size,
                              hipStream_t stream) {
  const float* x  = (const float*)d_in[0];   // [T, H]
  const float* gw = (const float*)d_in[1];   // [E, H]
  const float* w1 = (const float*)d_in[2];   // [E, F, H]
  const float* w2 = (const float*)d_in[3];   // [E, H, F]
  const float* w3 = (const float*)d_in[4];   // [E, F, H]

  float* final_out  = (float*)d_out;                       // [T, H]
  float* out_logits = final_out + (size_t)TT * HH;         // [T, E]

  char* ws = (char*)d_ws;
  int*   counts = (int*)(ws + 0);                             // 32 B
  int*   po     = (int*)(ws + 64);                            // 36 B
  int*   tokidx = (int*)(ws + 128);                           // 131072 B
  float* rww    = (float*)(ws + 128 + 131072);                // 131072 B
  unsigned short* xbf   = (unsigned short*)(ws + 262272);     // T*H*2   = 8388608
  unsigned short* wAbf  = (unsigned short*)(ws + 8650880);    // 33554432 (w1; later w2)
  unsigned short* w3bf  = (unsigned short*)(ws + 42205312);   // 33554432
  unsigned short* gated = (unsigned short*)(ws + 75759744);   // 9216*F*2 = 37748736
  // total ws use: 113,508,480 bytes

  hipMemsetAsync(counts, 0, 64, stream);
  hipMemsetAsync(final_out, 0, (size_t)TT * HH * sizeof(float), stream);

  const int nconv = (EE * FF * HH) / (256 * 8);  // 8192 blocks, exact
  conv_kernel<<<nconv, 256, 0, stream>>>(w1, wAbf);
  conv_kernel<<<nconv, 256, 0, stream>>>(w3, w3bf);
  router_kernel<<<TT, 256, 0, stream>>>(x, gw, out_logits, xbf, counts, tokidx, rww);
  scan_kernel<<<1, 64, 0, stream>>>(counts, po);
  up_gate_kernel<<<dim3(FF / 64, TT / 128, EE), 256, 0, stream>>>(
      xbf, wAbf, w3bf, counts, po, tokidx, gated);
  conv_kernel<<<nconv, 256, 0, stream>>>(w2, wAbf);  // reuse w1's buffer for w2
  down_kernel<<<dim3(HH / 128, TT / 128, EE), 256, 0, stream>>>(
      gated, wAbf, counts, po, tokidx, rww, final_out);
}

// Round 4
// 340.198 us; speedup vs baseline: 1.4842x; 1.0437x over previous
//
#include <hip/hip_runtime.h>
#include <hip/hip_bf16.h>

// MoE: B=2,S=2048 -> T=4096 tokens, H=1024, F=2048, E=8, TOPK=2
#define TT 4096
#define HH 1024
#define FF 2048
#define EE 8
#define NCONV 8192   // EE*FF*HH / (256*8)

typedef short short8_t __attribute__((ext_vector_type(8)));
typedef float f32x4 __attribute__((ext_vector_type(4)));

__device__ __forceinline__ unsigned short f2b(float f) {
  union { float f; unsigned u; } v; v.f = f;
  return (unsigned short)((v.u + 0x7fffu + ((v.u >> 16) & 1u)) >> 16);  // RNE
}

__device__ __forceinline__ short8_t pack8(float4 a, float4 b) {
  short8_t r;
  r[0] = (short)f2b(a.x); r[1] = (short)f2b(a.y);
  r[2] = (short)f2b(a.z); r[3] = (short)f2b(a.w);
  r[4] = (short)f2b(b.x); r[5] = (short)f2b(b.y);
  r[6] = (short)f2b(b.z); r[7] = (short)f2b(b.w);
  return r;
}

__device__ __forceinline__ void gload16(const unsigned short* g, unsigned short* l) {
  __builtin_amdgcn_global_load_lds(
      (const __attribute__((address_space(1))) void*)g,
      (__attribute__((address_space(3))) void*)l, 16, 0, 0);
}

__device__ __forceinline__ void conv_body(const float* __restrict__ src,
                                          unsigned short* __restrict__ dst,
                                          int b, int tid) {
  size_t i = ((size_t)b * 256 + tid) * 8;
  float4 a = *reinterpret_cast<const float4*>(src + i);
  float4 c = *reinterpret_cast<const float4*>(src + i + 4);
  *reinterpret_cast<short8_t*>(dst + i) = pack8(a, c);
}

// -------- Front: w1/w3 conv + router (logits, top-2, lists, x->bf16, zero final) --
__global__ __launch_bounds__(256) void front_kernel(
    const float* __restrict__ x, const float* __restrict__ gw,
    const float* __restrict__ w1, const float* __restrict__ w3,
    float* __restrict__ out_logits, float* __restrict__ final_out,
    unsigned short* __restrict__ xbf,
    unsigned short* __restrict__ w1bf, unsigned short* __restrict__ w3bf,
    int* __restrict__ counts, int* __restrict__ tokidx, float* __restrict__ rww)
{
  int tid = threadIdx.x;
  int b = blockIdx.x;
  if (b < NCONV)      { conv_body(w1, w1bf, b, tid); return; }
  if (b < 2 * NCONV)  { conv_body(w3, w3bf, b - NCONV, tid); return; }
  int t = b - 2 * NCONV;

  __shared__ float xs[HH];
  __shared__ float lg[EE];

  float4 v = reinterpret_cast<const float4*>(x + (size_t)t * HH)[tid];
  xs[tid * 4 + 0] = v.x; xs[tid * 4 + 1] = v.y;
  xs[tid * 4 + 2] = v.z; xs[tid * 4 + 3] = v.w;
  ushort4 b4;
  b4.x = f2b(v.x); b4.y = f2b(v.y); b4.z = f2b(v.z); b4.w = f2b(v.w);
  reinterpret_cast<ushort4*>(xbf + (size_t)t * HH)[tid] = b4;
  // zero this token's final_out row (replaces the big memset)
  float4 z4; z4.x = z4.y = z4.z = z4.w = 0.f;
  reinterpret_cast<float4*>(final_out + (size_t)t * HH)[tid] = z4;
  __syncthreads();

  int lane = tid & 63, wv = tid >> 6;
  for (int e = wv; e < EE; e += 4) {
    float s = 0.f;
    const float* g = gw + (size_t)e * HH;
#pragma unroll
    for (int j = 0; j < HH / 64; ++j) s += xs[lane + j * 64] * g[lane + j * 64];
#pragma unroll
    for (int off = 32; off > 0; off >>= 1) s += __shfl_down(s, off);
    if (lane == 0) lg[e] = s;
  }
  __syncthreads();

  if (tid == 0) {
    float l[EE];
#pragma unroll
    for (int e = 0; e < EE; ++e) {
      l[e] = lg[e];
      out_logits[(size_t)t * EE + e] = l[e];
    }
    int e0 = 0;
#pragma unroll
    for (int e = 1; e < EE; ++e) if (l[e] > l[e0]) e0 = e;
    int e1 = -1;
#pragma unroll
    for (int e = 0; e < EE; ++e) if (e != e0 && (e1 < 0 || l[e] > l[e1])) e1 = e;
    float p1 = expf(l[e1] - l[e0]);
    float w0 = 1.f / (1.f + p1);
    float w1v = p1 * w0;
    int pos0 = atomicAdd(&counts[e0], 1);
    tokidx[e0 * TT + pos0] = t; rww[e0 * TT + pos0] = w0;
    int pos1 = atomicAdd(&counts[e1], 1);
    tokidx[e1 * TT + pos1] = t; rww[e1 * TT + pos1] = w1v;
  }
}

// -------- Standalone conv for w2 (must run after up_gate; reuses w1's buffer) ----
__global__ __launch_bounds__(256) void conv_kernel(
    const float* __restrict__ src, unsigned short* __restrict__ dst)
{
  conv_body(src, dst, blockIdx.x, threadIdx.x);
}

// -------- Up-proj + gate: depth-2 prefetch, 3 LDS bufs, counted vmcnt ------------
__global__ __launch_bounds__(256) void up_gate_kernel(
    const unsigned short* __restrict__ xbf,
    const unsigned short* __restrict__ w1bf, const unsigned short* __restrict__ w3bf,
    const int* __restrict__ counts, const int* __restrict__ tokidx,
    unsigned short* __restrict__ gated)
{
  int e = blockIdx.z;
  int n = counts[e];
  int row0 = blockIdx.y * 128;
  if (row0 >= n) return;
  int fbase = blockIdx.x * 64;

  // padded prefix offset (replaces scan kernel; counts is L2-hot)
  int pe = 0;
  for (int q = 0; q < e; ++q) pe += (counts[q] + 127) & ~127;

  __shared__ unsigned short As[3][128 * 32];   // 3 x 8 KB
  __shared__ unsigned short B1s[3][64 * 32];   // 3 x 4 KB
  __shared__ unsigned short B3s[3][64 * 32];   // 3 x 4 KB

  int tid = threadIdx.x;
  int lane = tid & 63, wv = tid >> 6;
  int srow = wv * 16 + (lane >> 2);      // 0..63
  int skoff = (lane & 3) * 8;            // k-offset (elements)

  int r0 = min(row0 + srow, n - 1);
  int r1 = min(row0 + 64 + srow, n - 1);
  int t0 = tokidx[e * TT + r0];
  int t1 = tokidx[e * TT + r1];
  const unsigned short* ga0 = xbf + (size_t)t0 * HH + skoff;
  const unsigned short* ga1 = xbf + (size_t)t1 * HH + skoff;
  const unsigned short* gb1 = w1bf + ((size_t)e * FF + fbase + srow) * HH + skoff;
  const unsigned short* gb3 = w3bf + ((size_t)e * FF + fbase + srow) * HH + skoff;

#define STAGE_UG(tt, bb) do { int kk = (tt) * 32;            \
    gload16(ga0 + kk, &As[bb][wv * 512]);                    \
    gload16(ga1 + kk, &As[bb][2048 + wv * 512]);             \
    gload16(gb1 + kk, &B1s[bb][wv * 512]);                   \
    gload16(gb3 + kk, &B3s[bb][wv * 512]); } while (0)

  int wr = (wv >> 1) * 64, wc = (wv & 1) * 32;
  int fr = lane & 15, fk = (lane >> 4) * 8;

  f32x4 acc1[4][2], acc3[4][2];
#pragma unroll
  for (int m = 0; m < 4; ++m)
#pragma unroll
    for (int nn = 0; nn < 2; ++nn) { acc1[m][nn] = (f32x4)0.f; acc3[m][nn] = (f32x4)0.f; }

  const int NK = HH / 32;   // 32 K-tiles
  STAGE_UG(0, 0);
  STAGE_UG(1, 1);

  for (int t = 0; t < NK; ++t) {
    // counted wait: drain tile t's 4 loads, keep tile t+1's in flight
    if (t < NK - 1) asm volatile("s_waitcnt vmcnt(4)" ::: "memory");
    else            asm volatile("s_waitcnt vmcnt(0)" ::: "memory");
    __builtin_amdgcn_s_barrier();
    __builtin_amdgcn_sched_barrier(0);   // pin: no ds_read/stage hoists above barrier
    if (t + 2 < NK) STAGE_UG(t + 2, (t + 2) % 3);
    int cb = t % 3;

    short8_t a[4], b1f[2], b3f[2];
#pragma unroll
    for (int m = 0; m < 4; ++m)
      a[m] = *reinterpret_cast<const short8_t*>(&As[cb][(wr + m * 16 + fr) * 32 + fk]);
#pragma unroll
    for (int nn = 0; nn < 2; ++nn) {
      b1f[nn] = *reinterpret_cast<const short8_t*>(&B1s[cb][(wc + nn * 16 + fr) * 32 + fk]);
      b3f[nn] = *reinterpret_cast<const short8_t*>(&B3s[cb][(wc + nn * 16 + fr) * 32 + fk]);
    }
#pragma unroll
    for (int m = 0; m < 4; ++m)
#pragma unroll
      for (int nn = 0; nn < 2; ++nn) {
        acc1[m][nn] = __builtin_amdgcn_mfma_f32_16x16x32_bf16(a[m], b1f[nn], acc1[m][nn], 0, 0, 0);
        acc3[m][nn] = __builtin_amdgcn_mfma_f32_16x16x32_bf16(a[m], b3f[nn], acc3[m][nn], 0, 0, 0);
      }
  }
#undef STAGE_UG

  // epilogue: gated = silu(h1)*h3 -> bf16
  size_t gbase = ((size_t)pe + row0) * FF + fbase;
#pragma unroll
  for (int m = 0; m < 4; ++m) {
#pragma unroll
    for (int nn = 0; nn < 2; ++nn) {
      f32x4 h1v = acc1[m][nn], h3v = acc3[m][nn];
#pragma unroll
      for (int j = 0; j < 4; ++j) {
        float z = h1v[j];
        float val = (z / (1.f + expf(-z))) * h3v[j];
        int r = wr + m * 16 + (lane >> 4) * 4 + j;
        int c = wc + nn * 16 + fr;
        gated[gbase + (size_t)r * FF + c] = f2b(val);
      }
    }
  }
}

// -------- Down-proj + weighted scatter: depth-2 prefetch, 3 LDS bufs -------------
__global__ __launch_bounds__(256) void down_kernel(
    const unsigned short* __restrict__ gated,
    const unsigned short* __restrict__ w2bf,
    const int* __restrict__ counts, const int* __restrict__ tokidx,
    const float* __restrict__ rww,
    float* __restrict__ final_out)
{
  int e = blockIdx.z;
  int n = counts[e];
  int row0 = blockIdx.y * 128;
  if (row0 >= n) return;
  int hbase = blockIdx.x * 128;
  int valid = min(128, n - row0);

  int pe = 0;
  for (int q = 0; q < e; ++q) pe += (counts[q] + 127) & ~127;

  __shared__ unsigned short As[3][128 * 32];   // 3 x 8 KB
  __shared__ unsigned short Bs[3][128 * 32];   // 3 x 8 KB

  int tid = threadIdx.x;
  int lane = tid & 63, wv = tid >> 6;
  int srow = wv * 16 + (lane >> 2);
  int skoff = (lane & 3) * 8;

  const unsigned short* ga0 = gated + ((size_t)pe + row0 + srow) * FF + skoff;
  const unsigned short* ga1 = ga0 + (size_t)64 * FF;
  const unsigned short* gb0 = w2bf + ((size_t)e * HH + hbase + srow) * FF + skoff;
  const unsigned short* gb1 = gb0 + (size_t)64 * FF;

#define STAGE_DN(tt, bb) do { int kk = (tt) * 32;            \
    gload16(ga0 + kk, &As[bb][wv * 512]);                    \
    gload16(ga1 + kk, &As[bb][2048 + wv * 512]);             \
    gload16(gb0 + kk, &Bs[bb][wv * 512]);                    \
    gload16(gb1 + kk, &Bs[bb][2048 + wv * 512]); } while (0)

  int wr = (wv >> 1) * 64, wc = (wv & 1) * 64;
  int fr = lane & 15, fk = (lane >> 4) * 8;

  f32x4 acc[4][4];
#pragma unroll
  for (int m = 0; m < 4; ++m)
#pragma unroll
    for (int nn = 0; nn < 4; ++nn) acc[m][nn] = (f32x4)0.f;

  const int NK = FF / 32;   // 64 K-tiles
  STAGE_DN(0, 0);
  STAGE_DN(1, 1);

  for (int t = 0; t < NK; ++t) {
    if (t < NK - 1) asm volatile("s_waitcnt vmcnt(4)" ::: "memory");
    else            asm volatile("s_waitcnt vmcnt(0)" ::: "memory");
    __builtin_amdgcn_s_barrier();
    __builtin_amdgcn_sched_barrier(0);
    if (t + 2 < NK) STAGE_DN(t + 2, (t + 2) % 3);
    int cb = t % 3;

    short8_t a[4], bf[4];
#pragma unroll
    for (int m = 0; m < 4; ++m)
      a[m] = *reinterpret_cast<const short8_t*>(&As[cb][(wr + m * 16 + fr) * 32 + fk]);
#pragma unroll
    for (int nn = 0; nn < 4; ++nn)
      bf[nn] = *reinterpret_cast<const short8_t*>(&Bs[cb][(wc + nn * 16 + fr) * 32 + fk]);
#pragma unroll
    for (int m = 0; m < 4; ++m)
#pragma unroll
      for (int nn = 0; nn < 4; ++nn)
        acc[m][nn] = __builtin_amdgcn_mfma_f32_16x16x32_bf16(a[m], bf[nn], acc[m][nn], 0, 0, 0);
  }
#undef STAGE_DN

  // epilogue: final[t, h] += rw * out  (2 commutative f32 adds per element)
#pragma unroll
  for (int m = 0; m < 4; ++m) {
    int rbase = wr + m * 16 + (lane >> 4) * 4;
#pragma unroll
    for (int j = 0; j < 4; ++j) {
      int r = rbase + j;
      if (r < valid) {
        int t = tokidx[e * TT + row0 + r];
        float w = rww[e * TT + row0 + r];
#pragma unroll
        for (int nn = 0; nn < 4; ++nn) {
          int c = hbase + wc + nn * 16 + fr;
          atomicAdd(&final_out[(size_t)t * HH + c], w * acc[m][nn][j]);
        }
      }
    }
  }
}

extern "C" void kernel_launch(void* const* d_in, const int* in_sizes, int n_in,
                              void* d_out, int out_size, void* d_ws, size_t ws_size,
                              hipStream_t stream) {
  const float* x  = (const float*)d_in[0];   // [T, H]
  const float* gw = (const float*)d_in[1];   // [E, H]
  const float* w1 = (const float*)d_in[2];   // [E, F, H]
  const float* w2 = (const float*)d_in[3];   // [E, H, F]
  const float* w3 = (const float*)d_in[4];   // [E, F, H]

  float* final_out  = (float*)d_out;                       // [T, H]
  float* out_logits = final_out + (size_t)TT * HH;         // [T, E]

  char* ws = (char*)d_ws;
  int*   counts = (int*)(ws + 0);                             // 32 B
  int*   tokidx = (int*)(ws + 128);                           // 131072 B
  float* rww    = (float*)(ws + 128 + 131072);                // 131072 B
  unsigned short* xbf   = (unsigned short*)(ws + 262272);     // T*H*2   = 8388608
  unsigned short* wAbf  = (unsigned short*)(ws + 8650880);    // 33554432 (w1; later w2)
  unsigned short* w3bf  = (unsigned short*)(ws + 42205312);   // 33554432
  unsigned short* gated = (unsigned short*)(ws + 75759744);   // 9216*F*2 = 37748736
  // total ws use: 113,508,480 bytes

  hipMemsetAsync(counts, 0, 64, stream);
  front_kernel<<<2 * NCONV + TT, 256, 0, stream>>>(
      x, gw, w1, w3, out_logits, final_out, xbf, wAbf, w3bf, counts, tokidx, rww);
  up_gate_kernel<<<dim3(FF / 64, TT / 128, EE), 256, 0, stream>>>(
      xbf, wAbf, w3bf, counts, tokidx, gated);
  conv_kernel<<<NCONV, 256, 0, stream>>>(w2, wAbf);  // reuse w1's buffer for w2
  down_kernel<<<dim3(HH / 128, TT / 128, EE), 256, 0, stream>>>(
      gated, wAbf, counts, tokidx, rww, final_out);
}

// Round 5
// 265.473 us; speedup vs baseline: 1.9019x; 1.2815x over previous
//
#include <hip/hip_runtime.h>
#include <hip/hip_bf16.h>

// MoE: B=2,S=2048 -> T=4096 tokens, H=1024, F=2048, E=8, TOPK=2
#define TT 4096
#define HH 1024
#define FF 2048
#define EE 8
#define NCONV 8192   // EE*FF*HH / (256*8)

typedef short short8_t __attribute__((ext_vector_type(8)));
typedef float f32x4 __attribute__((ext_vector_type(4)));

__device__ __forceinline__ unsigned short f2b(float f) {
  union { float f; unsigned u; } v; v.f = f;
  return (unsigned short)((v.u + 0x7fffu + ((v.u >> 16) & 1u)) >> 16);  // RNE
}

__device__ __forceinline__ short8_t pack8(float4 a, float4 b) {
  short8_t r;
  r[0] = (short)f2b(a.x); r[1] = (short)f2b(a.y);
  r[2] = (short)f2b(a.z); r[3] = (short)f2b(a.w);
  r[4] = (short)f2b(b.x); r[5] = (short)f2b(b.y);
  r[6] = (short)f2b(b.z); r[7] = (short)f2b(b.w);
  return r;
}

__device__ __forceinline__ void gload16(const unsigned short* g, unsigned short* l) {
  __builtin_amdgcn_global_load_lds(
      (const __attribute__((address_space(1))) void*)g,
      (__attribute__((address_space(3))) void*)l, 16, 0, 0);
}

__device__ __forceinline__ void conv_body(const float* __restrict__ src,
                                          unsigned short* __restrict__ dst,
                                          int b, int tid) {
  size_t i = ((size_t)b * 256 + tid) * 8;
  float4 a = *reinterpret_cast<const float4*>(src + i);
  float4 c = *reinterpret_cast<const float4*>(src + i + 4);
  *reinterpret_cast<short8_t*>(dst + i) = pack8(a, c);
}

// -------- Front: router (atomic-free) FIRST, then w1/w3[/w2] convs --------------
__global__ __launch_bounds__(256) void front_kernel(
    const float* __restrict__ x, const float* __restrict__ gw,
    const float* __restrict__ w1, const float* __restrict__ w3,
    const float* __restrict__ w2,
    float* __restrict__ out_logits, float* __restrict__ final_out,
    unsigned short* __restrict__ xbf,
    unsigned short* __restrict__ w1bf, unsigned short* __restrict__ w3bf,
    unsigned short* __restrict__ w2bf, int do_w2,
    int* __restrict__ sel01, float2* __restrict__ w01)
{
  int tid = threadIdx.x;
  int b = blockIdx.x;
  if (b >= TT) {
    int cb = b - TT;
    if (cb < NCONV)          conv_body(w1, w1bf, cb, tid);
    else if (cb < 2 * NCONV) conv_body(w3, w3bf, cb - NCONV, tid);
    else                     conv_body(w2, w2bf, cb - 2 * NCONV, tid);
    return;
  }
  int t = b;

  __shared__ float xs[HH];
  __shared__ float lg[EE];

  float4 v = reinterpret_cast<const float4*>(x + (size_t)t * HH)[tid];
  xs[tid * 4 + 0] = v.x; xs[tid * 4 + 1] = v.y;
  xs[tid * 4 + 2] = v.z; xs[tid * 4 + 3] = v.w;
  ushort4 b4;
  b4.x = f2b(v.x); b4.y = f2b(v.y); b4.z = f2b(v.z); b4.w = f2b(v.w);
  reinterpret_cast<ushort4*>(xbf + (size_t)t * HH)[tid] = b4;
  // zero this token's final_out row (replaces big memset)
  float4 z4; z4.x = z4.y = z4.z = z4.w = 0.f;
  reinterpret_cast<float4*>(final_out + (size_t)t * HH)[tid] = z4;
  __syncthreads();

  int lane = tid & 63, wv = tid >> 6;
  for (int e = wv; e < EE; e += 4) {
    float s = 0.f;
    const float* g = gw + (size_t)e * HH;
#pragma unroll
    for (int j = 0; j < HH / 64; ++j) s += xs[lane + j * 64] * g[lane + j * 64];
#pragma unroll
    for (int off = 32; off > 0; off >>= 1) s += __shfl_down(s, off);
    if (lane == 0) lg[e] = s;
  }
  __syncthreads();

  if (tid < 8) out_logits[(size_t)t * EE + tid] = lg[tid];
  if (tid == 0) {
    float l[EE];
#pragma unroll
    for (int e = 0; e < EE; ++e) l[e] = lg[e];
    int e0 = 0;
#pragma unroll
    for (int e = 1; e < EE; ++e) if (l[e] > l[e0]) e0 = e;
    int e1 = -1;
#pragma unroll
    for (int e = 0; e < EE; ++e) if (e != e0 && (e1 < 0 || l[e] > l[e1])) e1 = e;
    float p1 = expf(l[e1] - l[e0]);
    float w0 = 1.f / (1.f + p1);
    float w1v = p1 * w0;
    sel01[t] = e0 | (e1 << 8);
    w01[t] = make_float2(w0, w1v);
  }
}

// -------- Build: per-expert compacted token lists, atomic-free, deterministic ----
__global__ __launch_bounds__(256) void build_kernel(
    const int* __restrict__ sel01, const float2* __restrict__ w01,
    int* __restrict__ counts, int* __restrict__ tokidx, float* __restrict__ rww)
{
  int e = blockIdx.x;
  int tid = threadIdx.x, lane = tid & 63, wv = tid >> 6;
  __shared__ int wsum[4];
  int base = 0;
  for (int t0 = 0; t0 < TT; t0 += 256) {
    int t = t0 + tid;
    int s = sel01[t];
    int e0 = s & 255, e1 = (s >> 8) & 255;
    bool hit = (e0 == e) || (e1 == e);
    float w = 0.f;
    if (hit) { float2 ww = w01[t]; w = (e0 == e) ? ww.x : ww.y; }
    unsigned long long m = __ballot(hit);
    int wpre = __popcll(m & ((1ull << lane) - 1));
    if (lane == 63) wsum[wv] = wpre + (hit ? 1 : 0);
    __syncthreads();
    int wbase = base;
    for (int q = 0; q < wv; ++q) wbase += wsum[q];
    if (hit) {
      int pos = wbase + wpre;
      tokidx[e * TT + pos] = t;
      rww[e * TT + pos] = w;
    }
    base += wsum[0] + wsum[1] + wsum[2] + wsum[3];
    __syncthreads();
  }
  if (tid == 0) counts[e] = base;
}

// -------- Standalone conv for w2 (fallback when ws too small: after up_gate) ----
__global__ __launch_bounds__(256) void conv_kernel(
    const float* __restrict__ src, unsigned short* __restrict__ dst)
{
  conv_body(src, dst, blockIdx.x, threadIdx.x);
}

// -------- Up-proj + gate: depth-2 prefetch, 3 LDS bufs, counted vmcnt ------------
__global__ __launch_bounds__(256) void up_gate_kernel(
    const unsigned short* __restrict__ xbf,
    const unsigned short* __restrict__ w1bf, const unsigned short* __restrict__ w3bf,
    const int* __restrict__ counts, const int* __restrict__ tokidx,
    unsigned short* __restrict__ gated)
{
  int e = blockIdx.z;
  int n = counts[e];
  int row0 = blockIdx.y * 128;
  if (row0 >= n) return;
  int fbase = blockIdx.x * 64;

  int pe = 0;
  for (int q = 0; q < e; ++q) pe += (counts[q] + 127) & ~127;

  __shared__ unsigned short As[3][128 * 32];   // 3 x 8 KB
  __shared__ unsigned short B1s[3][64 * 32];   // 3 x 4 KB
  __shared__ unsigned short B3s[3][64 * 32];   // 3 x 4 KB

  int tid = threadIdx.x;
  int lane = tid & 63, wv = tid >> 6;
  int srow = wv * 16 + (lane >> 2);      // 0..63
  int skoff = (lane & 3) * 8;            // k-offset (elements)

  int r0 = min(row0 + srow, n - 1);
  int r1 = min(row0 + 64 + srow, n - 1);
  int t0 = tokidx[e * TT + r0];
  int t1 = tokidx[e * TT + r1];
  const unsigned short* ga0 = xbf + (size_t)t0 * HH + skoff;
  const unsigned short* ga1 = xbf + (size_t)t1 * HH + skoff;
  const unsigned short* gb1 = w1bf + ((size_t)e * FF + fbase + srow) * HH + skoff;
  const unsigned short* gb3 = w3bf + ((size_t)e * FF + fbase + srow) * HH + skoff;

#define STAGE_UG(tt, bb) do { int kk = (tt) * 32;            \
    gload16(ga0 + kk, &As[bb][wv * 512]);                    \
    gload16(ga1 + kk, &As[bb][2048 + wv * 512]);             \
    gload16(gb1 + kk, &B1s[bb][wv * 512]);                   \
    gload16(gb3 + kk, &B3s[bb][wv * 512]); } while (0)

  int wr = (wv >> 1) * 64, wc = (wv & 1) * 32;
  int fr = lane & 15, fk = (lane >> 4) * 8;

  f32x4 acc1[4][2], acc3[4][2];
#pragma unroll
  for (int m = 0; m < 4; ++m)
#pragma unroll
    for (int nn = 0; nn < 2; ++nn) { acc1[m][nn] = (f32x4)0.f; acc3[m][nn] = (f32x4)0.f; }

  const int NK = HH / 32;   // 32 K-tiles
  STAGE_UG(0, 0);
  STAGE_UG(1, 1);

  for (int t = 0; t < NK; ++t) {
    if (t < NK - 1) asm volatile("s_waitcnt vmcnt(4)" ::: "memory");
    else            asm volatile("s_waitcnt vmcnt(0)" ::: "memory");
    __builtin_amdgcn_s_barrier();
    __builtin_amdgcn_sched_barrier(0);
    if (t + 2 < NK) STAGE_UG(t + 2, (t + 2) % 3);
    int cb = t % 3;

    short8_t a[4], b1f[2], b3f[2];
#pragma unroll
    for (int m = 0; m < 4; ++m)
      a[m] = *reinterpret_cast<const short8_t*>(&As[cb][(wr + m * 16 + fr) * 32 + fk]);
#pragma unroll
    for (int nn = 0; nn < 2; ++nn) {
      b1f[nn] = *reinterpret_cast<const short8_t*>(&B1s[cb][(wc + nn * 16 + fr) * 32 + fk]);
      b3f[nn] = *reinterpret_cast<const short8_t*>(&B3s[cb][(wc + nn * 16 + fr) * 32 + fk]);
    }
#pragma unroll
    for (int m = 0; m < 4; ++m)
#pragma unroll
      for (int nn = 0; nn < 2; ++nn) {
        acc1[m][nn] = __builtin_amdgcn_mfma_f32_16x16x32_bf16(a[m], b1f[nn], acc1[m][nn], 0, 0, 0);
        acc3[m][nn] = __builtin_amdgcn_mfma_f32_16x16x32_bf16(a[m], b3f[nn], acc3[m][nn], 0, 0, 0);
      }
  }
#undef STAGE_UG

  size_t gbase = ((size_t)pe + row0) * FF + fbase;
#pragma unroll
  for (int m = 0; m < 4; ++m) {
#pragma unroll
    for (int nn = 0; nn < 2; ++nn) {
      f32x4 h1v = acc1[m][nn], h3v = acc3[m][nn];
#pragma unroll
      for (int j = 0; j < 4; ++j) {
        float z = h1v[j];
        float val = (z / (1.f + expf(-z))) * h3v[j];
        int r = wr + m * 16 + (lane >> 4) * 4 + j;
        int c = wc + nn * 16 + fr;
        gated[gbase + (size_t)r * FF + c] = f2b(val);
      }
    }
  }
}

// -------- Down-proj + weighted scatter: depth-2 prefetch, 3 LDS bufs -------------
__global__ __launch_bounds__(256) void down_kernel(
    const unsigned short* __restrict__ gated,
    const unsigned short* __restrict__ w2bf,
    const int* __restrict__ counts, const int* __restrict__ tokidx,
    const float* __restrict__ rww,
    float* __restrict__ final_out)
{
  int e = blockIdx.z;
  int n = counts[e];
  int row0 = blockIdx.y * 128;
  if (row0 >= n) return;
  int hbase = blockIdx.x * 128;
  int valid = min(128, n - row0);

  int pe = 0;
  for (int q = 0; q < e; ++q) pe += (counts[q] + 127) & ~127;

  __shared__ unsigned short As[3][128 * 32];   // 3 x 8 KB
  __shared__ unsigned short Bs[3][128 * 32];   // 3 x 8 KB

  int tid = threadIdx.x;
  int lane = tid & 63, wv = tid >> 6;
  int srow = wv * 16 + (lane >> 2);
  int skoff = (lane & 3) * 8;

  const unsigned short* ga0 = gated + ((size_t)pe + row0 + srow) * FF + skoff;
  const unsigned short* ga1 = ga0 + (size_t)64 * FF;
  const unsigned short* gb0 = w2bf + ((size_t)e * HH + hbase + srow) * FF + skoff;
  const unsigned short* gb1 = gb0 + (size_t)64 * FF;

#define STAGE_DN(tt, bb) do { int kk = (tt) * 32;            \
    gload16(ga0 + kk, &As[bb][wv * 512]);                    \
    gload16(ga1 + kk, &As[bb][2048 + wv * 512]);             \
    gload16(gb0 + kk, &Bs[bb][wv * 512]);                    \
    gload16(gb1 + kk, &Bs[bb][2048 + wv * 512]); } while (0)

  int wr = (wv >> 1) * 64, wc = (wv & 1) * 64;
  int fr = lane & 15, fk = (lane >> 4) * 8;

  f32x4 acc[4][4];
#pragma unroll
  for (int m = 0; m < 4; ++m)
#pragma unroll
    for (int nn = 0; nn < 4; ++nn) acc[m][nn] = (f32x4)0.f;

  const int NK = FF / 32;   // 64 K-tiles
  STAGE_DN(0, 0);
  STAGE_DN(1, 1);

  for (int t = 0; t < NK; ++t) {
    if (t < NK - 1) asm volatile("s_waitcnt vmcnt(4)" ::: "memory");
    else            asm volatile("s_waitcnt vmcnt(0)" ::: "memory");
    __builtin_amdgcn_s_barrier();
    __builtin_amdgcn_sched_barrier(0);
    if (t + 2 < NK) STAGE_DN(t + 2, (t + 2) % 3);
    int cb = t % 3;

    short8_t a[4], bf[4];
#pragma unroll
    for (int m = 0; m < 4; ++m)
      a[m] = *reinterpret_cast<const short8_t*>(&As[cb][(wr + m * 16 + fr) * 32 + fk]);
#pragma unroll
    for (int nn = 0; nn < 4; ++nn)
      bf[nn] = *reinterpret_cast<const short8_t*>(&Bs[cb][(wc + nn * 16 + fr) * 32 + fk]);
#pragma unroll
    for (int m = 0; m < 4; ++m)
#pragma unroll
      for (int nn = 0; nn < 4; ++nn)
        acc[m][nn] = __builtin_amdgcn_mfma_f32_16x16x32_bf16(a[m], bf[nn], acc[m][nn], 0, 0, 0);
  }
#undef STAGE_DN

#pragma unroll
  for (int m = 0; m < 4; ++m) {
    int rbase = wr + m * 16 + (lane >> 4) * 4;
#pragma unroll
    for (int j = 0; j < 4; ++j) {
      int r = rbase + j;
      if (r < valid) {
        int t = tokidx[e * TT + row0 + r];
        float w = rww[e * TT + row0 + r];
#pragma unroll
        for (int nn = 0; nn < 4; ++nn) {
          int c = hbase + wc + nn * 16 + fr;
          atomicAdd(&final_out[(size_t)t * HH + c], w * acc[m][nn][j]);
        }
      }
    }
  }
}

extern "C" void kernel_launch(void* const* d_in, const int* in_sizes, int n_in,
                              void* d_out, int out_size, void* d_ws, size_t ws_size,
                              hipStream_t stream) {
  const float* x  = (const float*)d_in[0];   // [T, H]
  const float* gw = (const float*)d_in[1];   // [E, H]
  const float* w1 = (const float*)d_in[2];   // [E, F, H]
  const float* w2 = (const float*)d_in[3];   // [E, H, F]
  const float* w3 = (const float*)d_in[4];   // [E, F, H]

  float* final_out  = (float*)d_out;                       // [T, H]
  float* out_logits = final_out + (size_t)TT * HH;         // [T, E]

  char* ws = (char*)d_ws;
  int*    counts = (int*)(ws + 0);                            // 64 B
  int*    sel01  = (int*)(ws + 1024);                         // 16384
  float2* w01    = (float2*)(ws + 20480);                     // 32768
  int*    tokidx = (int*)(ws + 53248);                        // 131072
  float*  rww    = (float*)(ws + 184320);                     // 131072
  unsigned short* xbf   = (unsigned short*)(ws + 315392);     // 8388608
  unsigned short* w1bf  = (unsigned short*)(ws + 8704000);    // 33554432
  unsigned short* w3bf  = (unsigned short*)(ws + 42258432);   // 33554432
  unsigned short* gated = (unsigned short*)(ws + 75812864);   // 37748736
  const size_t base_end = 113561600;
  bool big = ws_size >= base_end + 33554432;                  // +32MB for w2bf
  unsigned short* w2bf = big ? (unsigned short*)(ws + base_end) : w1bf;

  int nconvs = big ? 3 : 2;
  front_kernel<<<TT + nconvs * NCONV, 256, 0, stream>>>(
      x, gw, w1, w3, w2, out_logits, final_out, xbf, w1bf, w3bf, w2bf,
      big ? 1 : 0, sel01, w01);
  build_kernel<<<EE, 256, 0, stream>>>(sel01, w01, counts, tokidx, rww);
  up_gate_kernel<<<dim3(FF / 64, TT / 128, EE), 256, 0, stream>>>(
      xbf, w1bf, w3bf, counts, tokidx, gated);
  if (!big) conv_kernel<<<NCONV, 256, 0, stream>>>(w2, w1bf);
  down_kernel<<<dim3(HH / 128, TT / 128, EE), 256, 0, stream>>>(
      gated, w2bf, counts, tokidx, rww, final_out);
}